// Round 14
// baseline (142.973 us; speedup 1.0000x reference)
//
#include <hip/hip_runtime.h>

// GRU (B=4096, T=512, I=1, H=32) + FC(32->12): K=32 MFMA, 8x replication,
// 2 rows/wave, 2048 waves = 2 per SIMD (hide the serial-chain latency that
// R13 left exposed: 260 idle cy/step at 1 wave/SIMD).
//
// R13 showed K=32 halves MFMA cycles (6 MFMA = 97 cy/wave), so the 2nd
// wave/SIMD now costs only ~194 cy MFMA/SIMD (R11's K=16 failure: 419).
// Columns: c = 2q + j (8 replicas q, row j). Lane (lg, c) owns ONE unit
//   u = ((q>>2)<<4) | (lg<<2) | (q&3),  row j     [R11-validated]
// Slot->k map chosen so the B-gather is the conflict-free swizzle set:
//   k(lg, i) = ((i>>2)<<4) | (lg<<2) | (i&3)
// => slot i's owner lane = (lane & 0b10001) | (i<<1), i.e. ds_swizzle
// pattern (i<<6)|0x11 (R11's validated patterns). 8 swizzles + 4 v_perm
// packs rebuild B from {h,h}-packed dwords. A and B use the same slot map;
// MFMA contracts slot-vs-slot so any consistent bijection is exact
// (R12/R13-validated). Zero LDS/barriers in the T-loop.
// Bias via post-select add (keeps VGPR under the 128 cap of (2,2)).
// h stays f32; f16 only as MFMA B operand. exp folding: r,z rows scaled by
// -log2e, n rows by +2log2e -> raw v_exp_f32 + v_rcp gates.

namespace {

typedef _Float16 f16;
typedef _Float16 f16x2 __attribute__((ext_vector_type(2)));
typedef _Float16 f16x8 __attribute__((ext_vector_type(8)));
typedef float    f32x4 __attribute__((ext_vector_type(4)));

constexpr int kT = 512;
constexpr float kL2E = 1.4426950408889634f;

__device__ __forceinline__ float fast_exp2(float a) {
#if __has_builtin(__builtin_amdgcn_exp2f)
    return __builtin_amdgcn_exp2f(a);
#else
    return exp2f(a);
#endif
}
__device__ __forceinline__ float fast_rcp(float a) {
#if __has_builtin(__builtin_amdgcn_rcpf)
    return __builtin_amdgcn_rcpf(a);
#else
    return 1.0f / a;
#endif
}

union B128 {
    int   w[4];
    f16x8 v;
};

// 8-way select: val = a[hb][(b1<<1)|b0], 7 cndmask
__device__ __forceinline__ float sel8(const f32x4& a0, const f32x4& a1,
                                      bool b0, bool b1, bool hb) {
    const float x01 = b0 ? a0[1] : a0[0];
    const float x23 = b0 ? a0[3] : a0[2];
    const float x   = b1 ? x23 : x01;
    const float y01 = b0 ? a1[1] : a1[0];
    const float y23 = b0 ? a1[3] : a1[2];
    const float y   = b1 ? y23 : y01;
    return hb ? y : x;
}

__global__ __launch_bounds__(64)
__attribute__((amdgpu_waves_per_eu(2, 2)))
void gru_k32d(
    const float* __restrict__ x,      // [4096, 512]
    const float* __restrict__ w_ih,   // [96]
    const float* __restrict__ w_hh,   // [96, 32]
    const float* __restrict__ b_ih,   // [96]
    const float* __restrict__ b_hh,   // [96]
    const float* __restrict__ fc_w,   // [12, 32]
    const float* __restrict__ fc_b,   // [12]
    float* __restrict__ out)          // [4096, 12]
{
    __shared__ float hf[2 * 33];      // FC epilogue only

    const int lane = threadIdx.x;     // single wave per block
    const int c    = lane & 15;       // B column = 2q + j
    const int lg   = lane >> 4;       // slot group
    const int q    = c >> 1;          // replica id 0..7
    const int j    = c & 1;           // batch row owned (within block's 2)
    const int blk  = blockIdx.x;

    // ---- A fragments, K=32, slot->k map k=((i>>2)<<4)|(lg<<2)|(i&3) ----
    f16x8 wA[3][2];
#pragma unroll
    for (int g = 0; g < 3; ++g) {
        const float s = (g < 2) ? -kL2E : 2.0f * kL2E;
#pragma unroll
        for (int hh = 0; hh < 2; ++hh) {
            f16x8 f;
#pragma unroll
            for (int i = 0; i < 8; ++i) {
                const int k = ((i >> 2) << 4) | (lg << 2) | (i & 3);
                f[i] = (f16)(s * w_hh[(g * 32 + hh * 16 + c) * 32 + k]);
            }
            wA[g][hh] = f;
        }
    }

    // ---- this lane's single unit and gate constants ----
    const int u = ((q >> 2) << 4) | (lg << 2) | (q & 3);
    const float cwr   = -kL2E * w_ih[u];
    const float cwz   = -kL2E * w_ih[u + 32];
    const float cwn   = 2.0f * kL2E * w_ih[u + 64];
    const float biasr = -kL2E * (b_ih[u] + b_hh[u]);
    const float biasz = -kL2E * (b_ih[u + 32] + b_hh[u + 32]);
    const float cbn   = 2.0f * kL2E * b_ih[u + 64];
    const float bhn   = 2.0f * kL2E * b_hh[u + 64];

    const bool b0 = (q & 1) != 0;   // reg select low bit  (v = q&3)
    const bool b1 = (q & 2) != 0;   // reg select high bit
    const bool hb = (q & 4) != 0;   // tile select (hh = q>>2)

    // ---- state ----
    float h = 0.0f;                   // h[row j][u], f32, never rounded
    B128 B;
    B.w[0] = 0; B.w[1] = 0; B.w[2] = 0; B.w[3] = 0;
    const f32x4 z4 = {0.0f, 0.0f, 0.0f, 0.0f};

    const float4* xrow = reinterpret_cast<const float4*>(
        x + ((size_t)blk * 2 + j) * kT);
    float4 xcur = xrow[0];

    for (int t0 = 0; t0 < kT; t0 += 4) {
        const int nq = (t0 + 4 < kT) ? (t0 >> 2) + 1 : (t0 >> 2);
        float4 xnext = xrow[nq];

#pragma unroll
        for (int tt = 0; tt < 4; ++tt) {
            const float xt = (tt == 0) ? xcur.x : (tt == 1) ? xcur.y
                           : (tt == 2) ? xcur.z : xcur.w;

            // ---- 6 independent K=32 MFMAs (C = 0, bias post-added) ----
            f32x4 aR[2], aZ[2], aN[2];
#pragma unroll
            for (int hh = 0; hh < 2; ++hh) {
                aR[hh] = __builtin_amdgcn_mfma_f32_16x16x32_f16(wA[0][hh], B.v, z4, 0, 0, 0);
                aZ[hh] = __builtin_amdgcn_mfma_f32_16x16x32_f16(wA[1][hh], B.v, z4, 0, 0, 0);
                aN[hh] = __builtin_amdgcn_mfma_f32_16x16x32_f16(wA[2][hh], B.v, z4, 0, 0, 0);
            }

            // ---- select this lane's preact triple (7 cndmask each) ----
            const float pr = sel8(aR[0], aR[1], b0, b1, hb);
            const float pz = sel8(aZ[0], aZ[1], b0, b1, hb);
            const float pn = sel8(aN[0], aN[1], b0, b1, hb);

            // ---- one gate update ----
            const float ar  = fmaf(xt, cwr, pr + biasr);
            const float az  = fmaf(xt, cwz, pz + biasz);
            const float an  = pn + bhn;
            const float inn = fmaf(xt, cwn, cbn);
            const float r = fast_rcp(1.0f + fast_exp2(ar));
            const float z = fast_rcp(1.0f + fast_exp2(az));
            const float n = fmaf(-2.0f,
                fast_rcp(1.0f + fast_exp2(fmaf(r, an, inn))), 1.0f);
            h = fmaf(z, h - n, n);

            // ---- rebuild B: cvt {h,h} + 8 swizzle + 4 v_perm ----
            const f16 hf16 = (f16)h;
            const int pk = __builtin_bit_cast(int, f16x2{hf16, hf16});
            const int s0 = __builtin_amdgcn_ds_swizzle(pk, 0x0011);  // i=0
            const int s1 = __builtin_amdgcn_ds_swizzle(pk, 0x0051);  // i=1
            const int s2 = __builtin_amdgcn_ds_swizzle(pk, 0x0091);  // i=2
            const int s3 = __builtin_amdgcn_ds_swizzle(pk, 0x00D1);  // i=3
            const int s4 = __builtin_amdgcn_ds_swizzle(pk, 0x0111);  // i=4
            const int s5 = __builtin_amdgcn_ds_swizzle(pk, 0x0151);  // i=5
            const int s6 = __builtin_amdgcn_ds_swizzle(pk, 0x0191);  // i=6
            const int s7 = __builtin_amdgcn_ds_swizzle(pk, 0x01D1);  // i=7
            B.w[0] = (int)__builtin_amdgcn_perm((unsigned)s1, (unsigned)s0, 0x07060100u);
            B.w[1] = (int)__builtin_amdgcn_perm((unsigned)s3, (unsigned)s2, 0x07060100u);
            B.w[2] = (int)__builtin_amdgcn_perm((unsigned)s5, (unsigned)s4, 0x07060100u);
            B.w[3] = (int)__builtin_amdgcn_perm((unsigned)s7, (unsigned)s6, 0x07060100u);
        }
        xcur = xnext;
    }

    // ---- FC epilogue: h[2][32] in LDS, 24 lanes compute outs ----
    hf[j * 33 + u] = h;
    __syncthreads();
    if (lane < 24) {
        const int row = lane / 12, o = lane % 12;
        float acc = fc_b[o];
#pragma unroll
        for (int k = 0; k < 32; ++k)
            acc = fmaf(fc_w[o * 32 + k], hf[row * 33 + k], acc);
        out[((size_t)blk * 2 + row) * 12 + o] = acc;
    }
}

}  // namespace

extern "C" void kernel_launch(void* const* d_in, const int* in_sizes, int n_in,
                              void* d_out, int out_size, void* d_ws, size_t ws_size,
                              hipStream_t stream) {
    const float* x    = (const float*)d_in[0];
    const float* w_ih = (const float*)d_in[1];
    const float* w_hh = (const float*)d_in[2];
    const float* b_ih = (const float*)d_in[3];
    const float* b_hh = (const float*)d_in[4];
    const float* fc_w = (const float*)d_in[5];
    const float* fc_b = (const float*)d_in[6];
    float* out = (float*)d_out;

    dim3 grid(2048);  // 4096 rows / 2 per wave -> 2 waves per SIMD chip-wide
    dim3 block(64);
    gru_k32d<<<grid, block, 0, stream>>>(x, w_ih, w_hh, b_ih, b_hh, fc_w, fc_b, out);
}

// Round 15
// 120.392 us; speedup vs baseline: 1.1876x; 1.1876x over previous
//
#include <hip/hip_runtime.h>

// GRU (B=4096, T=512, I=1, H=32) + FC(32->12): R13 structure (best: 118.6us)
// + product-rcp gate fusion.
//
// 1024 blocks x 64 threads (1 wave) = 1 wave/SIMD; wave owns 4 batch rows,
// replicated 4x in the B columns: col c = 4q + j. 6 independent
// mfma_f32_16x16x32_f16 (3 gates x 2 unit-halves), bias preloaded via C.
// Custom slot->k map (A and B use the same map; MFMA contracts slot-vs-slot
// so any consistent bijection is exact - R12/R13-validated):
//     k(lg, slot i) = ((i&1)<<4) | (lg<<2) | (i>>1)
// Ownership: lane (lg, c=4q+j) owns units u_lo=4lg+q, u_hi=16+4lg+q, row j;
// select reg q via 3-cndmask tree. B rebuild: slot pair (2p,2p+1) of lane
// (lg,c) = owner lane (lg,4p+j)'s packed {h_lo,h_hi} dword ->
// 4 conflict-free ds_swizzle (0x013/0x093/0x113/0x193), zero repack.
// Zero LDS/barriers in the T-loop.
//
// NEW vs R13: product-rcp sigmoid fusion - one rcp serves both r and z:
//   ip = rcp((1+Er)(1+Ez)); r = ip*(1+Ez); z = ip*(1+Er)
// (5 trans/update instead of 6; saves ~16 issue-cy/step at quarter-rate).
// R11/R14 lesson encoded here: symmetric 2-waves/SIMD phase-lock on the
// MFMA pipe and replication tax > latency-hiding gain -> stay at 4 rows,
// 1 wave/SIMD.
// h stays f32; f16 only as MFMA B operand (cvt_pkrtz). exp folding: r,z
// rows scaled by -log2e, n rows by +2log2e -> raw v_exp_f32 + v_rcp gates.

namespace {

typedef _Float16 f16;
typedef _Float16 f16x8 __attribute__((ext_vector_type(8)));
typedef float    f32x4 __attribute__((ext_vector_type(4)));

constexpr int kT = 512;
constexpr float kL2E = 1.4426950408889634f;

__device__ __forceinline__ float fast_exp2(float a) {
#if __has_builtin(__builtin_amdgcn_exp2f)
    return __builtin_amdgcn_exp2f(a);
#else
    return exp2f(a);
#endif
}
__device__ __forceinline__ float fast_rcp(float a) {
#if __has_builtin(__builtin_amdgcn_rcpf)
    return __builtin_amdgcn_rcpf(a);
#else
    return 1.0f / a;
#endif
}

union B128 {
    int   w[4];
    f16x8 v;
};

// 4-way select a[(b1<<1)|b0] via 3 cndmask
__device__ __forceinline__ float sel4(const f32x4& a, bool b0, bool b1) {
    const float x01 = b0 ? a[1] : a[0];
    const float x23 = b0 ? a[3] : a[2];
    return b1 ? x23 : x01;
}

__global__ __launch_bounds__(64)
__attribute__((amdgpu_waves_per_eu(1, 1)))
void gru_k32s2(
    const float* __restrict__ x,      // [4096, 512]
    const float* __restrict__ w_ih,   // [96]
    const float* __restrict__ w_hh,   // [96, 32]
    const float* __restrict__ b_ih,   // [96]
    const float* __restrict__ b_hh,   // [96]
    const float* __restrict__ fc_w,   // [12, 32]
    const float* __restrict__ fc_b,   // [12]
    float* __restrict__ out)          // [4096, 12]
{
    __shared__ float hf[4 * 33];      // FC epilogue only

    const int lane = threadIdx.x;     // single wave
    const int c    = lane & 15;       // B column = 4q + j
    const int lg   = lane >> 4;       // slot group
    const int q    = c >> 2;          // replica / owned-reg id 0..3
    const int j    = c & 3;           // batch row owned (within block's 4)
    const int blk  = blockIdx.x;

    // ---- A fragments, K=32, custom slot->k map, scale-folded ----
    f16x8 wA[3][2];
#pragma unroll
    for (int g = 0; g < 3; ++g) {
        const float s = (g < 2) ? -kL2E : 2.0f * kL2E;
#pragma unroll
        for (int hh = 0; hh < 2; ++hh) {
            f16x8 f;
#pragma unroll
            for (int i = 0; i < 8; ++i) {
                const int k = ((i & 1) << 4) | (lg << 2) | (i >> 1);
                f[i] = (f16)(s * w_hh[(g * 32 + hh * 16 + c) * 32 + k]);
            }
            wA[g][hh] = f;
        }
    }

    // ---- bias C operands: C[reg v][*] = bias(unit hh*16 + 4lg + v) ----
    f32x4 biasC[3][2];
#pragma unroll
    for (int hh = 0; hh < 2; ++hh)
#pragma unroll
        for (int v = 0; v < 4; ++v) {
            const int u = hh * 16 + 4 * lg + v;
            biasC[0][hh][v] = -kL2E * (b_ih[u] + b_hh[u]);
            biasC[1][hh][v] = -kL2E * (b_ih[u + 32] + b_hh[u + 32]);
            biasC[2][hh][v] = 2.0f * kL2E * b_hh[u + 64];
        }

    // ---- this lane's two units: u_lo = 4lg+q, u_hi = 16+4lg+q ----
    float cwr[2], cwz[2], cwn[2], cbn[2];
#pragma unroll
    for (int hh = 0; hh < 2; ++hh) {
        const int u = hh * 16 + 4 * lg + q;
        cwr[hh] = -kL2E * w_ih[u];
        cwz[hh] = -kL2E * w_ih[u + 32];
        cwn[hh] = 2.0f * kL2E * w_ih[u + 64];
        cbn[hh] = 2.0f * kL2E * b_ih[u + 64];
    }
    const bool b0 = (q & 1) != 0;
    const bool b1 = (q & 2) != 0;

    // ---- state ----
    float hlo = 0.0f, hhi = 0.0f;     // f32, never rounded
    B128 B;
    B.w[0] = 0; B.w[1] = 0; B.w[2] = 0; B.w[3] = 0;

    const float4* xrow = reinterpret_cast<const float4*>(
        x + ((size_t)blk * 4 + j) * kT);
    float4 xcur = xrow[0];

    for (int t0 = 0; t0 < kT; t0 += 4) {
        const int nq = (t0 + 4 < kT) ? (t0 >> 2) + 1 : (t0 >> 2);
        float4 xnext = xrow[nq];

#pragma unroll
        for (int tt = 0; tt < 4; ++tt) {
            const float xt = (tt == 0) ? xcur.x : (tt == 1) ? xcur.y
                           : (tt == 2) ? xcur.z : xcur.w;

            // ---- 6 independent K=32 MFMAs, bias via C ----
            f32x4 aR[2], aZ[2], aN[2];
#pragma unroll
            for (int hh = 0; hh < 2; ++hh) {
                aR[hh] = __builtin_amdgcn_mfma_f32_16x16x32_f16(wA[0][hh], B.v, biasC[0][hh], 0, 0, 0);
                aZ[hh] = __builtin_amdgcn_mfma_f32_16x16x32_f16(wA[1][hh], B.v, biasC[1][hh], 0, 0, 0);
                aN[hh] = __builtin_amdgcn_mfma_f32_16x16x32_f16(wA[2][hh], B.v, biasC[2][hh], 0, 0, 0);
            }

            // ---- two gate updates with product-rcp sigmoid fusion ----
#pragma unroll
            for (int hh = 0; hh < 2; ++hh) {
                const float pr = sel4(aR[hh], b0, b1);   // bias included (C)
                const float pz = sel4(aZ[hh], b0, b1);
                const float pn = sel4(aN[hh], b0, b1);
                const float ar  = fmaf(xt, cwr[hh], pr);
                const float az  = fmaf(xt, cwz[hh], pz);
                const float inn = fmaf(xt, cwn[hh], cbn[hh]);
                const float sr = 1.0f + fast_exp2(ar);   // 1 + 2^(-l2e*a_r)
                const float sz = 1.0f + fast_exp2(az);
                const float ip = fast_rcp(sr * sz);      // one rcp for r AND z
                const float r  = ip * sz;
                const float z  = ip * sr;
                const float n = fmaf(-2.0f,
                    fast_rcp(1.0f + fast_exp2(fmaf(r, pn, inn))), 1.0f);
                if (hh == 0) hlo = fmaf(z, hlo - n, n);
                else         hhi = fmaf(z, hhi - n, n);
            }

            // ---- rebuild B: 1 cvt_pkrtz + 4 conflict-free ds_swizzle ----
            const int pk = __builtin_bit_cast(int,
                __builtin_amdgcn_cvt_pkrtz(hlo, hhi));
            B.w[0] = __builtin_amdgcn_ds_swizzle(pk, 0x0013);  // p=0
            B.w[1] = __builtin_amdgcn_ds_swizzle(pk, 0x0093);  // p=1
            B.w[2] = __builtin_amdgcn_ds_swizzle(pk, 0x0113);  // p=2
            B.w[3] = __builtin_amdgcn_ds_swizzle(pk, 0x0193);  // p=3
        }
        xcur = xnext;
    }

    // ---- FC epilogue: h[4][32] in LDS, 48 lanes compute outs ----
    hf[j * 33 + 4 * lg + q]      = hlo;
    hf[j * 33 + 16 + 4 * lg + q] = hhi;
    __syncthreads();
    if (lane < 48) {
        const int row = lane / 12, o = lane % 12;
        float acc = fc_b[o];
#pragma unroll
        for (int k = 0; k < 32; ++k)
            acc = fmaf(fc_w[o * 32 + k], hf[row * 33 + k], acc);
        out[((size_t)blk * 4 + row) * 12 + o] = acc;
    }
}

}  // namespace

extern "C" void kernel_launch(void* const* d_in, const int* in_sizes, int n_in,
                              void* d_out, int out_size, void* d_ws, size_t ws_size,
                              hipStream_t stream) {
    const float* x    = (const float*)d_in[0];
    const float* w_ih = (const float*)d_in[1];
    const float* w_hh = (const float*)d_in[2];
    const float* b_ih = (const float*)d_in[3];
    const float* b_hh = (const float*)d_in[4];
    const float* fc_w = (const float*)d_in[5];
    const float* fc_b = (const float*)d_in[6];
    float* out = (float*)d_out;

    dim3 grid(1024);  // 4096 rows / 4 per wave -> 1 wave per SIMD chip-wide
    dim3 block(64);
    gru_k32s2<<<grid, block, 0, stream>>>(x, w_ih, w_hh, b_ih, b_hh, fc_w, fc_b, out);
}

// Round 16
// 107.547 us; speedup vs baseline: 1.3294x; 1.1194x over previous
//
#include <hip/hip_runtime.h>

// GRU (B=4096, T=512, I=1, H=32) + FC(32->12): unit-split 2-wave blocks.
//
// Block = 128 threads = 2 waves, owns 4 batch rows. Wave w owns hidden
// units [16w, 16w+16): it runs only 3 MFMAs (3 gates x its 16-unit tile,
// K=32, bias in C) and ONE gate update per lane. Per SIMD at 2 waves/SIMD
// (1024 blocks x 2 waves = 2048 waves): MFMA = 2x3 = 6 tiles = 96 cy,
// IDENTICAL to R13's single-wave cost - the R11/R14 replication tax is
// gone because the waves split the work instead of duplicating it, while
// per-wave gate VALU halves and the waves interleave their stalls.
//
// Cross-wave h exchange per step: 1 ds_write_b16 (own unit) + 1
// __syncthreads + 1 ds_read_b128 which lands DIRECTLY in the B operand
// (slot map k(lg,i) = 8*lg + i, the R12-validated map; A uses the same map;
// MFMA contracts slot-vs-slot so any consistent bijection is exact).
// hbuf double-buffered with compile-time parity (tt&1); the B-read is
// consumed by the MFMA before the next write+barrier -> WAR-safe with one
// barrier per step. 2-way bank aliases only (free, m136).
//
// Ownership (R13-validated pattern): lane (lg = L>>4, c = L&15), q = c>>2,
// j = c&3 owns unit u = 16w + 4lg + q, row j; select reg q via 3-cndmask.
// h stays f32 in registers; f16 only as the MFMA B operand. exp folding:
// r,z rows scaled by -log2e, n rows by +2log2e -> raw v_exp_f32 + v_rcp;
// product-rcp sigmoid fusion (R15-validated): one rcp serves r and z.

namespace {

typedef _Float16 f16;
typedef _Float16 f16x8 __attribute__((ext_vector_type(8)));
typedef float    f32x4 __attribute__((ext_vector_type(4)));

constexpr int kT = 512;
constexpr float kL2E = 1.4426950408889634f;

__device__ __forceinline__ float fast_exp2(float a) {
#if __has_builtin(__builtin_amdgcn_exp2f)
    return __builtin_amdgcn_exp2f(a);
#else
    return exp2f(a);
#endif
}
__device__ __forceinline__ float fast_rcp(float a) {
#if __has_builtin(__builtin_amdgcn_rcpf)
    return __builtin_amdgcn_rcpf(a);
#else
    return 1.0f / a;
#endif
}

// 4-way select a[(b1<<1)|b0] via 3 cndmask
__device__ __forceinline__ float sel4(const f32x4& a, bool b0, bool b1) {
    const float x01 = b0 ? a[1] : a[0];
    const float x23 = b0 ? a[3] : a[2];
    return b1 ? x23 : x01;
}

__global__ __launch_bounds__(128)
__attribute__((amdgpu_waves_per_eu(2, 2)))
void gru_2w(
    const float* __restrict__ x,      // [4096, 512]
    const float* __restrict__ w_ih,   // [96]
    const float* __restrict__ w_hh,   // [96, 32]
    const float* __restrict__ b_ih,   // [96]
    const float* __restrict__ b_hh,   // [96]
    const float* __restrict__ fc_w,   // [12, 32]
    const float* __restrict__ fc_b,   // [12]
    float* __restrict__ out)          // [4096, 12]
{
    __shared__ f16   hbuf[2][4][32];  // double-buffered h exchange
    __shared__ float hf[4 * 33];      // FC epilogue

    const int tid  = threadIdx.x;
    const int w    = tid >> 6;        // wave id: unit half [16w, 16w+16)
    const int lane = tid & 63;
    const int c    = lane & 15;       // B column = 4q + j
    const int lg   = lane >> 4;       // slot group: B slots = units 8lg..+7
    const int q    = c >> 2;          // owned-reg id 0..3
    const int j    = c & 3;           // batch row owned
    const int blk  = blockIdx.x;

    // ---- A fragments: 3 gates x this wave's 16-unit tile, K=32,
    //      slot map k(lg,i) = 8lg + i, scale-folded ----
    f16x8 wA[3];
#pragma unroll
    for (int g = 0; g < 3; ++g) {
        const float s = (g < 2) ? -kL2E : 2.0f * kL2E;
        f16x8 f;
#pragma unroll
        for (int i = 0; i < 8; ++i)
            f[i] = (f16)(s * w_hh[(g * 32 + w * 16 + c) * 32 + 8 * lg + i]);
        wA[g] = f;
    }

    // ---- bias C operands: C[reg v] = bias(unit 16w + 4lg + v) ----
    f32x4 biasC[3];
#pragma unroll
    for (int v = 0; v < 4; ++v) {
        const int u = w * 16 + 4 * lg + v;
        biasC[0][v] = -kL2E * (b_ih[u] + b_hh[u]);
        biasC[1][v] = -kL2E * (b_ih[u + 32] + b_hh[u + 32]);
        biasC[2][v] = 2.0f * kL2E * b_hh[u + 64];
    }

    // ---- this lane's unit u = 16w + 4lg + q ----
    const int u = w * 16 + 4 * lg + q;
    const float cwr = -kL2E * w_ih[u];
    const float cwz = -kL2E * w_ih[u + 32];
    const float cwn = 2.0f * kL2E * w_ih[u + 64];
    const float cbn = 2.0f * kL2E * b_ih[u + 64];
    const bool b0 = (q & 1) != 0;
    const bool b1 = (q & 2) != 0;

    // ---- state ----
    float h = 0.0f;
    f16x8 B = {(f16)0, (f16)0, (f16)0, (f16)0,
               (f16)0, (f16)0, (f16)0, (f16)0};

    const float4* xrow = reinterpret_cast<const float4*>(
        x + ((size_t)blk * 4 + j) * kT);
    float4 xcur = xrow[0];

    for (int t0 = 0; t0 < kT; t0 += 4) {
        const int nq = (t0 + 4 < kT) ? (t0 >> 2) + 1 : (t0 >> 2);
        float4 xnext = xrow[nq];

#pragma unroll
        for (int tt = 0; tt < 4; ++tt) {
            const float xt = (tt == 0) ? xcur.x : (tt == 1) ? xcur.y
                           : (tt == 2) ? xcur.z : xcur.w;
            const int buf = tt & 1;   // compile-time parity (t0 is even)

            // ---- 3 MFMAs: this wave's gate tiles, bias via C ----
            const f32x4 aR = __builtin_amdgcn_mfma_f32_16x16x32_f16(wA[0], B, biasC[0], 0, 0, 0);
            const f32x4 aZ = __builtin_amdgcn_mfma_f32_16x16x32_f16(wA[1], B, biasC[1], 0, 0, 0);
            const f32x4 aN = __builtin_amdgcn_mfma_f32_16x16x32_f16(wA[2], B, biasC[2], 0, 0, 0);

            // ---- one gate update (select reg q, product-rcp fusion) ----
            const float pr = sel4(aR, b0, b1);
            const float pz = sel4(aZ, b0, b1);
            const float pn = sel4(aN, b0, b1);
            const float ar  = fmaf(xt, cwr, pr);
            const float az  = fmaf(xt, cwz, pz);
            const float inn = fmaf(xt, cwn, cbn);
            const float sr = 1.0f + fast_exp2(ar);
            const float sz = 1.0f + fast_exp2(az);
            const float ip = fast_rcp(sr * sz);
            const float r  = ip * sz;
            const float z  = ip * sr;
            const float n = fmaf(-2.0f,
                fast_rcp(1.0f + fast_exp2(fmaf(r, pn, inn))), 1.0f);
            h = fmaf(z, h - n, n);

            // ---- exchange: write own unit, barrier, read full row ----
            hbuf[buf][j][u] = (f16)h;
            __syncthreads();
            B = *reinterpret_cast<const f16x8*>(&hbuf[buf][j][8 * lg]);
        }
        xcur = xnext;
    }

    // ---- FC epilogue: h[4][32] f32 in LDS (128 lanes = 128 h values) ----
    hf[j * 33 + u] = h;
    __syncthreads();
    if (tid < 48) {
        const int row = tid / 12, o = tid % 12;
        float acc = fc_b[o];
#pragma unroll
        for (int k = 0; k < 32; ++k)
            acc = fmaf(fc_w[o * 32 + k], hf[row * 33 + k], acc);
        out[((size_t)blk * 4 + row) * 12 + o] = acc;
    }
}

}  // namespace

extern "C" void kernel_launch(void* const* d_in, const int* in_sizes, int n_in,
                              void* d_out, int out_size, void* d_ws, size_t ws_size,
                              hipStream_t stream) {
    const float* x    = (const float*)d_in[0];
    const float* w_ih = (const float*)d_in[1];
    const float* w_hh = (const float*)d_in[2];
    const float* b_ih = (const float*)d_in[3];
    const float* b_hh = (const float*)d_in[4];
    const float* fc_w = (const float*)d_in[5];
    const float* fc_b = (const float*)d_in[6];
    float* out = (float*)d_out;

    dim3 grid(1024);   // 4096 rows / 4 per block
    dim3 block(128);   // 2 waves: unit-split, 2048 waves = 2/SIMD
    gru_2w<<<grid, block, 0, stream>>>(x, w_ih, w_hh, b_ih, b_hh, fc_w, fc_b, out);
}